// Round 1
// baseline (1140.507 us; speedup 1.0000x reference)
//
#include <hip/hip_runtime.h>

// GCN: N=100000 nodes, D=64, E=1600000 edges, 3 GCN steps, dropout p=0.3.
// Inputs: h [N,D] f32, vals [E] f32, u [3,N,D] f32, rows [E] i32, cols [E] i32.
// Output: (h + sum_l cur_l) / 4, f32 [N,D].

constexpr int   N_NODES  = 100000;
constexpr int   D        = 64;
constexpr int   E_EDGES  = 1600000;
constexpr int   ND       = N_NODES * D;
constexpr float P_DROP   = 0.3f;
constexpr float INV_KEEP = 1.0f / (1.0f - P_DROP);

// out = src  (float4-vectorized)
__global__ void copy_f4(const float4* __restrict__ src, float4* __restrict__ dst, int n4) {
    int i = blockIdx.x * blockDim.x + threadIdx.x;
    if (i < n4) dst[i] = src[i];
}

// t = cur * ((u > p) ? 1/(1-p) : 0)
__global__ void dropout_f4(const float4* __restrict__ cur, const float4* __restrict__ u,
                           float4* __restrict__ t, int n4) {
    int i = blockIdx.x * blockDim.x + threadIdx.x;
    if (i < n4) {
        float4 c = cur[i];
        float4 uu = u[i];
        float4 o;
        o.x = (uu.x > P_DROP) ? c.x * INV_KEEP : 0.0f;
        o.y = (uu.y > P_DROP) ? c.y * INV_KEEP : 0.0f;
        o.z = (uu.z > P_DROP) ? c.z * INV_KEEP : 0.0f;
        o.w = (uu.w > P_DROP) ? c.w * INV_KEEP : 0.0f;
        t[i] = o;
    }
}

// One 64-lane wave per edge; lane = feature dim. Coalesced gather of src row,
// coalesced atomicAdd into dst row.
__global__ void scatter_edges(const float* __restrict__ t, const float* __restrict__ vals,
                              const int* __restrict__ rows, const int* __restrict__ cols,
                              float* __restrict__ nxt) {
    int e = blockIdx.x * (blockDim.x >> 6) + (threadIdx.x >> 6);
    int d = threadIdx.x & 63;
    if (e >= E_EDGES) return;
    int c = cols[e];
    int r = rows[e];
    float v = vals[e];
    atomicAdd(&nxt[(size_t)r * D + d], v * t[(size_t)c * D + d]);
}

// acc += x
__global__ void add_f4(float4* __restrict__ acc, const float4* __restrict__ x, int n4) {
    int i = blockIdx.x * blockDim.x + threadIdx.x;
    if (i < n4) {
        float4 a = acc[i];
        float4 b = x[i];
        a.x += b.x; a.y += b.y; a.z += b.z; a.w += b.w;
        acc[i] = a;
    }
}

// acc *= s
__global__ void scale_f4(float4* __restrict__ acc, float s, int n4) {
    int i = blockIdx.x * blockDim.x + threadIdx.x;
    if (i < n4) {
        float4 a = acc[i];
        a.x *= s; a.y *= s; a.z *= s; a.w *= s;
        acc[i] = a;
    }
}

extern "C" void kernel_launch(void* const* d_in, const int* in_sizes, int n_in,
                              void* d_out, int out_size, void* d_ws, size_t ws_size,
                              hipStream_t stream) {
    const float* h    = (const float*)d_in[0];
    const float* vals = (const float*)d_in[1];
    const float* u    = (const float*)d_in[2];
    const int*   rows = (const int*)d_in[3];
    const int*   cols = (const int*)d_in[4];
    float* out = (float*)d_out;

    float* T  = (float*)d_ws;        // dropped features   [ND]
    float* B0 = T + ND;              // layer output buf   [ND]
    float* B1 = B0 + ND;             // layer output buf   [ND]

    const int n4 = ND / 4;
    dim3 blk(256);
    int gElem = (n4 + 255) / 256;
    int gScat = (E_EDGES + 3) / 4;   // 4 edges per 256-thread block (1 wave/edge)

    // acc = h (in d_out)
    copy_f4<<<gElem, blk, 0, stream>>>((const float4*)h, (float4*)out, n4);

    const float* cur = h;
    float* bufs[2] = {B0, B1};
    for (int l = 0; l < 3; ++l) {
        float* nxt = bufs[l & 1];
        dropout_f4<<<gElem, blk, 0, stream>>>((const float4*)cur,
                                              (const float4*)(u + (size_t)l * ND),
                                              (float4*)T, n4);
        hipMemsetAsync(nxt, 0, (size_t)ND * sizeof(float), stream);
        scatter_edges<<<gScat, blk, 0, stream>>>(T, vals, rows, cols, nxt);
        add_f4<<<gElem, blk, 0, stream>>>((float4*)out, (const float4*)nxt, n4);
        cur = nxt;
    }
    scale_f4<<<gElem, blk, 0, stream>>>((float4*)out, 0.25f, n4);
}

// Round 2
// 882.728 us; speedup vs baseline: 1.2920x; 1.2920x over previous
//
#include <hip/hip_runtime.h>

// GCN: N=100000 nodes, D=64, E=1600000 edges, 3 GCN steps, dropout p=0.3.
// Strategy: build CSR once per call (atomic-free hot path), then per layer a
// gather-reduce SpMM (wave per node, lane per feature) with fused epilogue:
//   out += s;  t_next = dropout(s)   (and final *0.25 fused into layer 2).

constexpr int   N_NODES  = 100000;
constexpr int   D        = 64;
constexpr int   E_EDGES  = 1600000;
constexpr int   ND       = N_NODES * D;
constexpr float P_DROP   = 0.3f;
constexpr float INV_KEEP = 1.0f / (1.0f - P_DROP);

// ---------- CSR build ----------

__global__ void count_deg(const int* __restrict__ rows, int* __restrict__ deg) {
    int e = blockIdx.x * blockDim.x + threadIdx.x;
    if (e < E_EDGES) atomicAdd(&deg[rows[e]], 1);
}

// Single 1024-thread block: exclusive scan of deg -> rowptr (+ cursor copy).
__global__ void scan_deg(const int* __restrict__ deg, int* __restrict__ rowptr,
                         int* __restrict__ cursor) {
    __shared__ int sums[1024];
    const int tid = threadIdx.x;
    const int CHUNK = (N_NODES + 1023) / 1024;
    int beg = tid * CHUNK;
    int end = min(beg + CHUNK, N_NODES);
    int s = 0;
    for (int i = beg; i < end; ++i) s += deg[i];
    sums[tid] = s;
    __syncthreads();
    for (int off = 1; off < 1024; off <<= 1) {
        int v = (tid >= off) ? sums[tid - off] : 0;
        __syncthreads();
        sums[tid] += v;
        __syncthreads();
    }
    int run = (tid == 0) ? 0 : sums[tid - 1];
    for (int i = beg; i < end; ++i) {
        rowptr[i] = run;
        cursor[i] = run;
        run += deg[i];
    }
    if (tid == 1023) rowptr[N_NODES] = run;
}

__global__ void build_csr(const int* __restrict__ rows, const int* __restrict__ cols,
                          const float* __restrict__ vals, int* __restrict__ cursor,
                          int* __restrict__ scols, float* __restrict__ svals) {
    int e = blockIdx.x * blockDim.x + threadIdx.x;
    if (e >= E_EDGES) return;
    int r = rows[e];
    int p = atomicAdd(&cursor[r], 1);
    scols[p] = cols[e];
    svals[p] = vals[e];
}

// ---------- layer kernels ----------

// out = h;  t0 = dropout(h, u0)
__global__ void init_out_dropout(const float4* __restrict__ h, const float4* __restrict__ u,
                                 float4* __restrict__ out, float4* __restrict__ t, int n4) {
    int i = blockIdx.x * blockDim.x + threadIdx.x;
    if (i >= n4) return;
    float4 c = h[i];
    float4 uu = u[i];
    out[i] = c;
    float4 o;
    o.x = (uu.x > P_DROP) ? c.x * INV_KEEP : 0.0f;
    o.y = (uu.y > P_DROP) ? c.y * INV_KEEP : 0.0f;
    o.z = (uu.z > P_DROP) ? c.z * INV_KEEP : 0.0f;
    o.w = (uu.w > P_DROP) ? c.w * INV_KEEP : 0.0f;
    t[i] = o;
}

// Wave per node, lane per feature:
//   s = sum_{edges into node} val * t[col]
//   out[node] = (out[node] + s) * out_scale
//   if HAS_NEXT: t_next[node] = dropout(s, u_next)
template <bool HAS_NEXT>
__global__ void spmm_csr(const float* __restrict__ t, const int* __restrict__ rowptr,
                         const int* __restrict__ scols, const float* __restrict__ svals,
                         const float* __restrict__ u_next, float* __restrict__ t_next,
                         float* __restrict__ out, float out_scale) {
    int node = blockIdx.x * (blockDim.x >> 6) + (threadIdx.x >> 6);
    int d = threadIdx.x & 63;
    if (node >= N_NODES) return;
    int beg = rowptr[node];
    int end = rowptr[node + 1];
    float s = 0.0f;
    for (int i = beg; i < end; ++i) {
        int c = scols[i];
        float v = svals[i];
        s = fmaf(v, t[(size_t)c * D + d], s);
    }
    size_t idx = (size_t)node * D + d;
    out[idx] = (out[idx] + s) * out_scale;
    if (HAS_NEXT) {
        float uu = u_next[idx];
        t_next[idx] = (uu > P_DROP) ? s * INV_KEEP : 0.0f;
    }
}

extern "C" void kernel_launch(void* const* d_in, const int* in_sizes, int n_in,
                              void* d_out, int out_size, void* d_ws, size_t ws_size,
                              hipStream_t stream) {
    const float* h    = (const float*)d_in[0];
    const float* vals = (const float*)d_in[1];
    const float* u    = (const float*)d_in[2];
    const int*   rows = (const int*)d_in[3];
    const int*   cols = (const int*)d_in[4];
    float* out = (float*)d_out;

    // workspace layout
    float* T0     = (float*)d_ws;            // [ND]
    float* T1     = T0 + ND;                 // [ND]
    float* svals  = T1 + ND;                 // [E]
    int*   scols  = (int*)(svals + E_EDGES); // [E]
    int*   rowptr = scols + E_EDGES;         // [N+1]
    int*   cursor = rowptr + (N_NODES + 1);  // [N]
    int*   deg    = cursor + N_NODES;        // [N]

    const int n4 = ND / 4;
    dim3 blk(256);
    int gElem = (n4 + 255) / 256;
    int gEdge = (E_EDGES + 255) / 256;
    int gNode = (N_NODES + 3) / 4;  // 4 waves (nodes) per 256-thread block

    // ---- CSR build (once per call) ----
    hipMemsetAsync(deg, 0, (size_t)N_NODES * sizeof(int), stream);
    count_deg<<<gEdge, blk, 0, stream>>>(rows, deg);
    scan_deg<<<1, 1024, 0, stream>>>(deg, rowptr, cursor);
    build_csr<<<gEdge, blk, 0, stream>>>(rows, cols, vals, cursor, scols, svals);

    // ---- layer 0 prologue: out = h, T0 = dropout(h, u0) ----
    init_out_dropout<<<gElem, blk, 0, stream>>>((const float4*)h, (const float4*)u,
                                                (float4*)out, (float4*)T0, n4);

    // ---- layer 0: out += S(T0); T1 = dropout(S, u1) ----
    spmm_csr<true><<<gNode, blk, 0, stream>>>(T0, rowptr, scols, svals,
                                              u + (size_t)1 * ND, T1, out, 1.0f);
    // ---- layer 1: out += S(T1); T0 = dropout(S, u2) ----
    spmm_csr<true><<<gNode, blk, 0, stream>>>(T1, rowptr, scols, svals,
                                              u + (size_t)2 * ND, T0, out, 1.0f);
    // ---- layer 2: out = (out + S(T0)) * 0.25 ----
    spmm_csr<false><<<gNode, blk, 0, stream>>>(T0, rowptr, scols, svals,
                                               nullptr, nullptr, out, 0.25f);
}

// Round 3
// 673.151 us; speedup vs baseline: 1.6943x; 1.3113x over previous
//
#include <hip/hip_runtime.h>

// GCN: N=100000 nodes, D=64, E=1600000 edges, 3 GCN steps, dropout p=0.3.
// CSR built once per call (parallel two-level scan), then per layer a
// gather-reduce SpMM (wave per node, lane per feature) with fused epilogue.

constexpr int   N_NODES  = 100000;
constexpr int   D        = 64;
constexpr int   E_EDGES  = 1600000;
constexpr int   ND       = N_NODES * D;
constexpr float P_DROP   = 0.3f;
constexpr float INV_KEEP = 1.0f / (1.0f - P_DROP);

constexpr int SEG         = 512;                          // elements per scan block
constexpr int SCAN_BLOCKS = (N_NODES + SEG - 1) / SEG;    // 196

// ---------- CSR build ----------

__global__ void count_deg(const int* __restrict__ rows, int* __restrict__ deg) {
    int e = blockIdx.x * blockDim.x + threadIdx.x;
    if (e < E_EDGES) atomicAdd(&deg[rows[e]], 1);
}

// Level 1: per-block sum of a SEG-element segment of deg.
__global__ void scan_block_sums(const int* __restrict__ deg, int* __restrict__ bsum) {
    __shared__ int red[256];
    int base = blockIdx.x * SEG;
    int tid = threadIdx.x;
    int i0 = base + 2 * tid, i1 = i0 + 1;
    int v = 0;
    if (i0 < N_NODES) v += deg[i0];
    if (i1 < N_NODES) v += deg[i1];
    red[tid] = v;
    __syncthreads();
    for (int off = 128; off > 0; off >>= 1) {
        if (tid < off) red[tid] += red[tid + off];
        __syncthreads();
    }
    if (tid == 0) bsum[blockIdx.x] = red[0];
}

// Level 2: single block scans the SCAN_BLOCKS partial sums -> exclusive offsets.
__global__ void scan_bsums(const int* __restrict__ bsum, int* __restrict__ boff,
                           int* __restrict__ rowptr) {
    __shared__ int s[256];
    int tid = threadIdx.x;
    int v = (tid < SCAN_BLOCKS) ? bsum[tid] : 0;
    s[tid] = v;
    __syncthreads();
    for (int off = 1; off < 256; off <<= 1) {
        int t = (tid >= off) ? s[tid - off] : 0;
        __syncthreads();
        s[tid] += t;
        __syncthreads();
    }
    if (tid < SCAN_BLOCKS) boff[tid] = s[tid] - v;   // exclusive
    if (tid == 0) rowptr[N_NODES] = E_EDGES;         // total degree is E by construction
}

// Level 3: per-block local exclusive scan + global offset -> rowptr & cursor.
__global__ void scan_write(const int* __restrict__ deg, const int* __restrict__ boff,
                           int* __restrict__ rowptr, int* __restrict__ cursor) {
    __shared__ int s[256];
    int base = blockIdx.x * SEG;
    int tid = threadIdx.x;
    int i0 = base + 2 * tid, i1 = i0 + 1;
    int v0 = (i0 < N_NODES) ? deg[i0] : 0;
    int v1 = (i1 < N_NODES) ? deg[i1] : 0;
    int pair = v0 + v1;
    s[tid] = pair;
    __syncthreads();
    for (int off = 1; off < 256; off <<= 1) {
        int t = (tid >= off) ? s[tid - off] : 0;
        __syncthreads();
        s[tid] += t;
        __syncthreads();
    }
    int excl = boff[blockIdx.x] + s[tid] - pair;
    if (i0 < N_NODES) { rowptr[i0] = excl;      cursor[i0] = excl; }
    if (i1 < N_NODES) { rowptr[i1] = excl + v0; cursor[i1] = excl + v0; }
}

// Fill packed CSR edges: sedge[p] = (col, bits(val)).
__global__ void build_csr(const int* __restrict__ rows, const int* __restrict__ cols,
                          const float* __restrict__ vals, int* __restrict__ cursor,
                          int2* __restrict__ sedge) {
    int e = blockIdx.x * blockDim.x + threadIdx.x;
    if (e >= E_EDGES) return;
    int r = rows[e];
    int p = atomicAdd(&cursor[r], 1);
    sedge[p] = make_int2(cols[e], __float_as_int(vals[e]));
}

// ---------- layer kernels ----------

// out = h;  t0 = dropout(h, u0)
__global__ void init_out_dropout(const float4* __restrict__ h, const float4* __restrict__ u,
                                 float4* __restrict__ out, float4* __restrict__ t, int n4) {
    int i = blockIdx.x * blockDim.x + threadIdx.x;
    if (i >= n4) return;
    float4 c = h[i];
    float4 uu = u[i];
    out[i] = c;
    float4 o;
    o.x = (uu.x > P_DROP) ? c.x * INV_KEEP : 0.0f;
    o.y = (uu.y > P_DROP) ? c.y * INV_KEEP : 0.0f;
    o.z = (uu.z > P_DROP) ? c.z * INV_KEEP : 0.0f;
    o.w = (uu.w > P_DROP) ? c.w * INV_KEEP : 0.0f;
    t[i] = o;
}

// Wave per node, lane per feature:
//   s = sum_{in-edges} val * t[col];  out[node] = (out[node] + s) * out_scale
//   if HAS_NEXT: t_next[node] = dropout(s, u_next)
template <bool HAS_NEXT>
__global__ void spmm_csr(const float* __restrict__ t, const int* __restrict__ rowptr,
                         const int2* __restrict__ sedge,
                         const float* __restrict__ u_next, float* __restrict__ t_next,
                         float* __restrict__ out, float out_scale) {
    int node = blockIdx.x * (blockDim.x >> 6) + (threadIdx.x >> 6);
    int d = threadIdx.x & 63;
    if (node >= N_NODES) return;
    int beg = rowptr[node];
    int end = rowptr[node + 1];
    float s = 0.0f;
    for (int i = beg; i < end; ++i) {
        int2 ev = sedge[i];
        s = fmaf(__int_as_float(ev.y), t[(size_t)ev.x * D + d], s);
    }
    size_t idx = (size_t)node * D + d;
    out[idx] = (out[idx] + s) * out_scale;
    if (HAS_NEXT) {
        float uu = u_next[idx];
        t_next[idx] = (uu > P_DROP) ? s * INV_KEEP : 0.0f;
    }
}

extern "C" void kernel_launch(void* const* d_in, const int* in_sizes, int n_in,
                              void* d_out, int out_size, void* d_ws, size_t ws_size,
                              hipStream_t stream) {
    const float* h    = (const float*)d_in[0];
    const float* vals = (const float*)d_in[1];
    const float* u    = (const float*)d_in[2];
    const int*   rows = (const int*)d_in[3];
    const int*   cols = (const int*)d_in[4];
    float* out = (float*)d_out;

    // workspace layout
    float* T0     = (float*)d_ws;                 // [ND]
    float* T1     = T0 + ND;                      // [ND]
    int2*  sedge  = (int2*)(T1 + ND);             // [E] packed (col, val)
    int*   rowptr = (int*)(sedge + E_EDGES);      // [N+1]
    int*   cursor = rowptr + (N_NODES + 1);       // [N]
    int*   deg    = cursor + N_NODES;             // [N]
    int*   bsum   = deg + N_NODES;                // [SCAN_BLOCKS]
    int*   boff   = bsum + SCAN_BLOCKS;           // [SCAN_BLOCKS]

    const int n4 = ND / 4;
    dim3 blk(256);
    int gElem = (n4 + 255) / 256;
    int gEdge = (E_EDGES + 255) / 256;
    int gNode = (N_NODES + 3) / 4;  // 4 waves (nodes) per 256-thread block

    // ---- CSR build (once per call) ----
    hipMemsetAsync(deg, 0, (size_t)N_NODES * sizeof(int), stream);
    count_deg<<<gEdge, blk, 0, stream>>>(rows, deg);
    scan_block_sums<<<SCAN_BLOCKS, blk, 0, stream>>>(deg, bsum);
    scan_bsums<<<1, blk, 0, stream>>>(bsum, boff, rowptr);
    scan_write<<<SCAN_BLOCKS, blk, 0, stream>>>(deg, boff, rowptr, cursor);
    build_csr<<<gEdge, blk, 0, stream>>>(rows, cols, vals, cursor, sedge);

    // ---- layer 0 prologue: out = h, T0 = dropout(h, u0) ----
    init_out_dropout<<<gElem, blk, 0, stream>>>((const float4*)h, (const float4*)u,
                                                (float4*)out, (float4*)T0, n4);

    // ---- layer 0: out += S(T0); T1 = dropout(S, u1) ----
    spmm_csr<true><<<gNode, blk, 0, stream>>>(T0, rowptr, sedge,
                                              u + (size_t)1 * ND, T1, out, 1.0f);
    // ---- layer 1: out += S(T1); T0 = dropout(S, u2) ----
    spmm_csr<true><<<gNode, blk, 0, stream>>>(T1, rowptr, sedge,
                                              u + (size_t)2 * ND, T0, out, 1.0f);
    // ---- layer 2: out = (out + S(T0)) * 0.25 ----
    spmm_csr<false><<<gNode, blk, 0, stream>>>(T0, rowptr, sedge,
                                               nullptr, nullptr, out, 0.25f);
}

// Round 4
// 446.361 us; speedup vs baseline: 2.5551x; 1.5081x over previous
//
#include <hip/hip_runtime.h>

// GCN: N=100000 nodes, D=64, E=1600000 edges, 3 GCN steps, dropout p=0.3.
// CSR built once per call (parallel two-level scan), then per layer a
// gather-reduce SpMM (wave per node, lane per feature), edge loop unrolled
// 4-wide for memory-level parallelism, with fused dropout/accum epilogue.

constexpr int   N_NODES  = 100000;
constexpr int   D        = 64;
constexpr int   E_EDGES  = 1600000;
constexpr int   ND       = N_NODES * D;
constexpr float P_DROP   = 0.3f;
constexpr float INV_KEEP = 1.0f / (1.0f - P_DROP);

constexpr int SEG         = 512;                          // elements per scan block
constexpr int SCAN_BLOCKS = (N_NODES + SEG - 1) / SEG;    // 196

// ---------- CSR build ----------

__global__ void count_deg(const int* __restrict__ rows, int* __restrict__ deg) {
    int e = blockIdx.x * blockDim.x + threadIdx.x;
    if (e < E_EDGES) atomicAdd(&deg[rows[e]], 1);
}

// Level 1: per-block sum of a SEG-element segment of deg.
__global__ void scan_block_sums(const int* __restrict__ deg, int* __restrict__ bsum) {
    __shared__ int red[256];
    int base = blockIdx.x * SEG;
    int tid = threadIdx.x;
    int i0 = base + 2 * tid, i1 = i0 + 1;
    int v = 0;
    if (i0 < N_NODES) v += deg[i0];
    if (i1 < N_NODES) v += deg[i1];
    red[tid] = v;
    __syncthreads();
    for (int off = 128; off > 0; off >>= 1) {
        if (tid < off) red[tid] += red[tid + off];
        __syncthreads();
    }
    if (tid == 0) bsum[blockIdx.x] = red[0];
}

// Level 2: single block scans the SCAN_BLOCKS partial sums -> exclusive offsets.
__global__ void scan_bsums(const int* __restrict__ bsum, int* __restrict__ boff,
                           int* __restrict__ rowptr) {
    __shared__ int s[256];
    int tid = threadIdx.x;
    int v = (tid < SCAN_BLOCKS) ? bsum[tid] : 0;
    s[tid] = v;
    __syncthreads();
    for (int off = 1; off < 256; off <<= 1) {
        int t = (tid >= off) ? s[tid - off] : 0;
        __syncthreads();
        s[tid] += t;
        __syncthreads();
    }
    if (tid < SCAN_BLOCKS) boff[tid] = s[tid] - v;   // exclusive
    if (tid == 0) rowptr[N_NODES] = E_EDGES;         // total degree is E by construction
}

// Level 3: per-block local exclusive scan + global offset -> rowptr & cursor.
__global__ void scan_write(const int* __restrict__ deg, const int* __restrict__ boff,
                           int* __restrict__ rowptr, int* __restrict__ cursor) {
    __shared__ int s[256];
    int base = blockIdx.x * SEG;
    int tid = threadIdx.x;
    int i0 = base + 2 * tid, i1 = i0 + 1;
    int v0 = (i0 < N_NODES) ? deg[i0] : 0;
    int v1 = (i1 < N_NODES) ? deg[i1] : 0;
    int pair = v0 + v1;
    s[tid] = pair;
    __syncthreads();
    for (int off = 1; off < 256; off <<= 1) {
        int t = (tid >= off) ? s[tid - off] : 0;
        __syncthreads();
        s[tid] += t;
        __syncthreads();
    }
    int excl = boff[blockIdx.x] + s[tid] - pair;
    if (i0 < N_NODES) { rowptr[i0] = excl;      cursor[i0] = excl; }
    if (i1 < N_NODES) { rowptr[i1] = excl + v0; cursor[i1] = excl + v0; }
}

// Fill packed CSR edges: sedge[p] = (col, bits(val)).
__global__ void build_csr(const int* __restrict__ rows, const int* __restrict__ cols,
                          const float* __restrict__ vals, int* __restrict__ cursor,
                          int2* __restrict__ sedge) {
    int e = blockIdx.x * blockDim.x + threadIdx.x;
    if (e >= E_EDGES) return;
    int r = rows[e];
    int p = atomicAdd(&cursor[r], 1);
    sedge[p] = make_int2(cols[e], __float_as_int(vals[e]));
}

// ---------- layer kernels ----------

// out = h;  t0 = dropout(h, u0)
__global__ void init_out_dropout(const float4* __restrict__ h, const float4* __restrict__ u,
                                 float4* __restrict__ out, float4* __restrict__ t, int n4) {
    int i = blockIdx.x * blockDim.x + threadIdx.x;
    if (i >= n4) return;
    float4 c = h[i];
    float4 uu = u[i];
    out[i] = c;
    float4 o;
    o.x = (uu.x > P_DROP) ? c.x * INV_KEEP : 0.0f;
    o.y = (uu.y > P_DROP) ? c.y * INV_KEEP : 0.0f;
    o.z = (uu.z > P_DROP) ? c.z * INV_KEEP : 0.0f;
    o.w = (uu.w > P_DROP) ? c.w * INV_KEEP : 0.0f;
    t[i] = o;
}

// Wave per node, lane per feature. Edge loop unrolled x4: 4 independent row
// gathers in flight per wave (MLP) instead of a serial load->fma chain.
//   s = sum_{in-edges} val * t[col];  out[node] = (out[node] + s) * out_scale
//   if HAS_NEXT: t_next[node] = dropout(s, u_next)
template <bool HAS_NEXT>
__global__ void spmm_csr(const float* __restrict__ t, const int* __restrict__ rowptr,
                         const int2* __restrict__ sedge,
                         const float* __restrict__ u_next, float* __restrict__ t_next,
                         float* __restrict__ out, float out_scale) {
    int node = blockIdx.x * (blockDim.x >> 6) + (threadIdx.x >> 6);
    int d = threadIdx.x & 63;
    if (node >= N_NODES) return;
    int beg = rowptr[node];
    int end = rowptr[node + 1];
    float s = 0.0f;
    int i = beg;
    for (; i + 4 <= end; i += 4) {
        int2 e0 = sedge[i];
        int2 e1 = sedge[i + 1];
        int2 e2 = sedge[i + 2];
        int2 e3 = sedge[i + 3];
        float f0 = t[(size_t)e0.x * D + d];
        float f1 = t[(size_t)e1.x * D + d];
        float f2 = t[(size_t)e2.x * D + d];
        float f3 = t[(size_t)e3.x * D + d];
        s = fmaf(__int_as_float(e0.y), f0, s);
        s = fmaf(__int_as_float(e1.y), f1, s);
        s = fmaf(__int_as_float(e2.y), f2, s);
        s = fmaf(__int_as_float(e3.y), f3, s);
    }
    for (; i < end; ++i) {
        int2 ev = sedge[i];
        s = fmaf(__int_as_float(ev.y), t[(size_t)ev.x * D + d], s);
    }
    size_t idx = (size_t)node * D + d;
    out[idx] = (out[idx] + s) * out_scale;
    if (HAS_NEXT) {
        float uu = u_next[idx];
        t_next[idx] = (uu > P_DROP) ? s * INV_KEEP : 0.0f;
    }
}

extern "C" void kernel_launch(void* const* d_in, const int* in_sizes, int n_in,
                              void* d_out, int out_size, void* d_ws, size_t ws_size,
                              hipStream_t stream) {
    const float* h    = (const float*)d_in[0];
    const float* vals = (const float*)d_in[1];
    const float* u    = (const float*)d_in[2];
    const int*   rows = (const int*)d_in[3];
    const int*   cols = (const int*)d_in[4];
    float* out = (float*)d_out;

    // workspace layout
    float* T0     = (float*)d_ws;                 // [ND]
    float* T1     = T0 + ND;                      // [ND]
    int2*  sedge  = (int2*)(T1 + ND);             // [E] packed (col, val)
    int*   rowptr = (int*)(sedge + E_EDGES);      // [N+1]
    int*   cursor = rowptr + (N_NODES + 1);       // [N]
    int*   deg    = cursor + N_NODES;             // [N]
    int*   bsum   = deg + N_NODES;                // [SCAN_BLOCKS]
    int*   boff   = bsum + SCAN_BLOCKS;           // [SCAN_BLOCKS]

    const int n4 = ND / 4;
    dim3 blk(256);
    int gElem = (n4 + 255) / 256;
    int gEdge = (E_EDGES + 255) / 256;
    int gNode = (N_NODES + 3) / 4;  // 4 waves (nodes) per 256-thread block

    // ---- CSR build (once per call) ----
    hipMemsetAsync(deg, 0, (size_t)N_NODES * sizeof(int), stream);
    count_deg<<<gEdge, blk, 0, stream>>>(rows, deg);
    scan_block_sums<<<SCAN_BLOCKS, blk, 0, stream>>>(deg, bsum);
    scan_bsums<<<1, blk, 0, stream>>>(bsum, boff, rowptr);
    scan_write<<<SCAN_BLOCKS, blk, 0, stream>>>(deg, boff, rowptr, cursor);
    build_csr<<<gEdge, blk, 0, stream>>>(rows, cols, vals, cursor, sedge);

    // ---- layer 0 prologue: out = h, T0 = dropout(h, u0) ----
    init_out_dropout<<<gElem, blk, 0, stream>>>((const float4*)h, (const float4*)u,
                                                (float4*)out, (float4*)T0, n4);

    // ---- layer 0: out += S(T0); T1 = dropout(S, u1) ----
    spmm_csr<true><<<gNode, blk, 0, stream>>>(T0, rowptr, sedge,
                                              u + (size_t)1 * ND, T1, out, 1.0f);
    // ---- layer 1: out += S(T1); T0 = dropout(S, u2) ----
    spmm_csr<true><<<gNode, blk, 0, stream>>>(T1, rowptr, sedge,
                                              u + (size_t)2 * ND, T0, out, 1.0f);
    // ---- layer 2: out = (out + S(T0)) * 0.25 ----
    spmm_csr<false><<<gNode, blk, 0, stream>>>(T0, rowptr, sedge,
                                               nullptr, nullptr, out, 0.25f);
}

// Round 5
// 379.595 us; speedup vs baseline: 3.0045x; 1.1759x over previous
//
#include <hip/hip_runtime.h>

// GCN: N=100000 nodes, D=64, E=1600000 edges, 3 GCN steps, dropout p=0.3.
// CSR build: count/scan (two-level), then a 2-phase edge permutation that
// avoids cross-XCD partial-line write amplification:
//   P2 bucket_scatter: per-block LDS histogram + per-bucket run reservation ->
//       runs written contiguously by one CU (line-local writes combine in L2).
//   P3 csr_finalize: one workgroup per bucket, LDS row cursors, writes land in
//       one ~64KB region through a single XCD L2 -> full-line writebacks.
// SpMM: wave per node, lane per feature, 4x unrolled gather, fused epilogue.

constexpr int   N_NODES  = 100000;
constexpr int   D        = 64;
constexpr int   E_EDGES  = 1600000;
constexpr int   ND       = N_NODES * D;
constexpr float P_DROP   = 0.3f;
constexpr float INV_KEEP = 1.0f / (1.0f - P_DROP);

constexpr int SEG         = 512;                          // deg-scan segment
constexpr int SCAN_BLOCKS = (N_NODES + SEG - 1) / SEG;    // 196

constexpr int BROWS   = 512;                              // rows per bucket
constexpr int NB      = (N_NODES + BROWS - 1) / BROWS;    // 196 buckets
constexpr int TILE    = 2048;                             // edges per P2 block
constexpr int EPT     = TILE / 256;                       // 8 edges per thread
constexpr int P2_GRID = (E_EDGES + TILE - 1) / TILE;      // 782

// ---------- degree + rowptr ----------

__global__ void count_deg(const int* __restrict__ rows, int* __restrict__ deg) {
    int e = blockIdx.x * blockDim.x + threadIdx.x;
    if (e < E_EDGES) atomicAdd(&deg[rows[e]], 1);
}

__global__ void scan_block_sums(const int* __restrict__ deg, int* __restrict__ bsum) {
    __shared__ int red[256];
    int base = blockIdx.x * SEG;
    int tid = threadIdx.x;
    int i0 = base + 2 * tid, i1 = i0 + 1;
    int v = 0;
    if (i0 < N_NODES) v += deg[i0];
    if (i1 < N_NODES) v += deg[i1];
    red[tid] = v;
    __syncthreads();
    for (int off = 128; off > 0; off >>= 1) {
        if (tid < off) red[tid] += red[tid + off];
        __syncthreads();
    }
    if (tid == 0) bsum[blockIdx.x] = red[0];
}

__global__ void scan_bsums(const int* __restrict__ bsum, int* __restrict__ boff,
                           int* __restrict__ rowptr) {
    __shared__ int s[256];
    int tid = threadIdx.x;
    int v = (tid < SCAN_BLOCKS) ? bsum[tid] : 0;
    s[tid] = v;
    __syncthreads();
    for (int off = 1; off < 256; off <<= 1) {
        int t = (tid >= off) ? s[tid - off] : 0;
        __syncthreads();
        s[tid] += t;
        __syncthreads();
    }
    if (tid < SCAN_BLOCKS) boff[tid] = s[tid] - v;   // exclusive
    if (tid == 0) rowptr[N_NODES] = E_EDGES;
}

__global__ void scan_write(const int* __restrict__ deg, const int* __restrict__ boff,
                           int* __restrict__ rowptr) {
    __shared__ int s[256];
    int base = blockIdx.x * SEG;
    int tid = threadIdx.x;
    int i0 = base + 2 * tid, i1 = i0 + 1;
    int v0 = (i0 < N_NODES) ? deg[i0] : 0;
    int v1 = (i1 < N_NODES) ? deg[i1] : 0;
    int pair = v0 + v1;
    s[tid] = pair;
    __syncthreads();
    for (int off = 1; off < 256; off <<= 1) {
        int t = (tid >= off) ? s[tid - off] : 0;
        __syncthreads();
        s[tid] += t;
        __syncthreads();
    }
    int excl = boff[blockIdx.x] + s[tid] - pair;
    if (i0 < N_NODES) rowptr[i0] = excl;
    if (i1 < N_NODES) rowptr[i1] = excl + v0;
}

// bucket_cursor[b] = rowptr[b*BROWS]  (bucket regions of the CSR array)
__global__ void init_bcur(const int* __restrict__ rowptr, int* __restrict__ bucket_cursor) {
    int b = threadIdx.x;
    if (b < NB) {
        int r = b * BROWS;
        bucket_cursor[b] = rowptr[r < N_NODES ? r : N_NODES];
    }
}

// ---------- P2: bucket-major scatter (write-combining friendly) ----------
// tmp[dest] = int2{ (localrow<<17)|col, bits(val) }, bucket-major.
__global__ void bucket_scatter(const int* __restrict__ rows, const int* __restrict__ cols,
                               const float* __restrict__ vals, int* __restrict__ bucket_cursor,
                               int2* __restrict__ tmp) {
    __shared__ int lc[NB];
    __shared__ int gcur[NB];
    int tid = threadIdx.x;
    int base = blockIdx.x * TILE;

    if (tid < NB) lc[tid] = 0;
    __syncthreads();

    int r[EPT], c[EPT], b[EPT];
    float v[EPT];
#pragma unroll
    for (int k = 0; k < EPT; ++k) {
        int e = base + k * 256 + tid;
        if (e < E_EDGES) {
            r[k] = rows[e];
            c[k] = cols[e];
            v[k] = vals[e];
            b[k] = r[k] >> 9;                 // BROWS = 512
            atomicAdd(&lc[b[k]], 1);
        } else {
            b[k] = -1;
        }
    }
    __syncthreads();

    if (tid < NB && lc[tid] > 0)
        gcur[tid] = atomicAdd(&bucket_cursor[tid], lc[tid]);
    __syncthreads();

#pragma unroll
    for (int k = 0; k < EPT; ++k) {
        if (b[k] >= 0) {
            int dest = atomicAdd(&gcur[b[k]], 1);
            int meta = ((r[k] & (BROWS - 1)) << 17) | c[k];
            tmp[dest] = make_int2(meta, __float_as_int(v[k]));
        }
    }
}

// ---------- P3: per-bucket CSR finalize (single-XCD write region) ----------
__global__ void csr_finalize(const int* __restrict__ rowptr, const int2* __restrict__ tmp,
                             int2* __restrict__ sedge) {
    __shared__ int rcur[BROWS];
    int b = blockIdx.x;
    int tid = threadIdx.x;
    int rbase = b * BROWS;
    int rcount = min(BROWS, N_NODES - rbase);

    for (int i = tid; i < rcount; i += 256) rcur[i] = rowptr[rbase + i];
    __syncthreads();

    int seg_beg = rowptr[rbase];
    int seg_end = rowptr[(rbase + BROWS < N_NODES) ? rbase + BROWS : N_NODES];
    for (int i = seg_beg + tid; i < seg_end; i += 256) {
        int2 ev = tmp[i];
        int lr = ev.x >> 17;
        int cc = ev.x & 0x1FFFF;
        int p = atomicAdd(&rcur[lr], 1);
        sedge[p] = make_int2(cc, ev.y);
    }
}

// ---------- layer kernels ----------

__global__ void init_out_dropout(const float4* __restrict__ h, const float4* __restrict__ u,
                                 float4* __restrict__ out, float4* __restrict__ t, int n4) {
    int i = blockIdx.x * blockDim.x + threadIdx.x;
    if (i >= n4) return;
    float4 c = h[i];
    float4 uu = u[i];
    out[i] = c;
    float4 o;
    o.x = (uu.x > P_DROP) ? c.x * INV_KEEP : 0.0f;
    o.y = (uu.y > P_DROP) ? c.y * INV_KEEP : 0.0f;
    o.z = (uu.z > P_DROP) ? c.z * INV_KEEP : 0.0f;
    o.w = (uu.w > P_DROP) ? c.w * INV_KEEP : 0.0f;
    t[i] = o;
}

// Wave per node, lane per feature; 4-wide unrolled gather for MLP.
template <bool HAS_NEXT>
__global__ void spmm_csr(const float* __restrict__ t, const int* __restrict__ rowptr,
                         const int2* __restrict__ sedge,
                         const float* __restrict__ u_next, float* __restrict__ t_next,
                         float* __restrict__ out, float out_scale) {
    int node = blockIdx.x * (blockDim.x >> 6) + (threadIdx.x >> 6);
    int d = threadIdx.x & 63;
    if (node >= N_NODES) return;
    int beg = rowptr[node];
    int end = rowptr[node + 1];
    float s = 0.0f;
    int i = beg;
    for (; i + 4 <= end; i += 4) {
        int2 e0 = sedge[i];
        int2 e1 = sedge[i + 1];
        int2 e2 = sedge[i + 2];
        int2 e3 = sedge[i + 3];
        float f0 = t[(size_t)e0.x * D + d];
        float f1 = t[(size_t)e1.x * D + d];
        float f2 = t[(size_t)e2.x * D + d];
        float f3 = t[(size_t)e3.x * D + d];
        s = fmaf(__int_as_float(e0.y), f0, s);
        s = fmaf(__int_as_float(e1.y), f1, s);
        s = fmaf(__int_as_float(e2.y), f2, s);
        s = fmaf(__int_as_float(e3.y), f3, s);
    }
    for (; i < end; ++i) {
        int2 ev = sedge[i];
        s = fmaf(__int_as_float(ev.y), t[(size_t)ev.x * D + d], s);
    }
    size_t idx = (size_t)node * D + d;
    out[idx] = (out[idx] + s) * out_scale;
    if (HAS_NEXT) {
        float uu = u_next[idx];
        t_next[idx] = (uu > P_DROP) ? s * INV_KEEP : 0.0f;
    }
}

extern "C" void kernel_launch(void* const* d_in, const int* in_sizes, int n_in,
                              void* d_out, int out_size, void* d_ws, size_t ws_size,
                              hipStream_t stream) {
    const float* h    = (const float*)d_in[0];
    const float* vals = (const float*)d_in[1];
    const float* u    = (const float*)d_in[2];
    const int*   rows = (const int*)d_in[3];
    const int*   cols = (const int*)d_in[4];
    float* out = (float*)d_out;

    // workspace layout (tmp aliases T1: tmp is dead before layer 0 writes T1)
    float* T0     = (float*)d_ws;                 // [ND]
    float* T1     = T0 + ND;                      // [ND]
    int2*  tmp    = (int2*)T1;                    // [E]  (alias, build-phase only)
    int2*  sedge  = (int2*)(T1 + ND);             // [E] packed (col, val)
    int*   rowptr = (int*)(sedge + E_EDGES);      // [N+1]
    int*   deg    = rowptr + (N_NODES + 1);       // [N]
    int*   bsum   = deg + N_NODES;                // [SCAN_BLOCKS]
    int*   boff   = bsum + SCAN_BLOCKS;           // [SCAN_BLOCKS]
    int*   bcur   = boff + SCAN_BLOCKS;           // [NB]

    const int n4 = ND / 4;
    dim3 blk(256);
    int gElem = (n4 + 255) / 256;
    int gEdge = (E_EDGES + 255) / 256;
    int gNode = (N_NODES + 3) / 4;

    // ---- CSR build ----
    hipMemsetAsync(deg, 0, (size_t)N_NODES * sizeof(int), stream);
    count_deg<<<gEdge, blk, 0, stream>>>(rows, deg);
    scan_block_sums<<<SCAN_BLOCKS, blk, 0, stream>>>(deg, bsum);
    scan_bsums<<<1, blk, 0, stream>>>(bsum, boff, rowptr);
    scan_write<<<SCAN_BLOCKS, blk, 0, stream>>>(deg, boff, rowptr);
    init_bcur<<<1, blk, 0, stream>>>(rowptr, bcur);
    bucket_scatter<<<P2_GRID, blk, 0, stream>>>(rows, cols, vals, bcur, tmp);
    csr_finalize<<<NB, blk, 0, stream>>>(rowptr, tmp, sedge);

    // ---- layer 0 prologue: out = h, T0 = dropout(h, u0) ----
    init_out_dropout<<<gElem, blk, 0, stream>>>((const float4*)h, (const float4*)u,
                                                (float4*)out, (float4*)T0, n4);

    // ---- layers ----
    spmm_csr<true><<<gNode, blk, 0, stream>>>(T0, rowptr, sedge,
                                              u + (size_t)1 * ND, T1, out, 1.0f);
    spmm_csr<true><<<gNode, blk, 0, stream>>>(T1, rowptr, sedge,
                                              u + (size_t)2 * ND, T0, out, 1.0f);
    spmm_csr<false><<<gNode, blk, 0, stream>>>(T0, rowptr, sedge,
                                               nullptr, nullptr, out, 0.25f);
}

// Round 6
// 365.867 us; speedup vs baseline: 3.1173x; 1.0375x over previous
//
#include <hip/hip_runtime.h>
#include <hip/hip_bf16.h>

// GCN: N=100000 nodes, D=64, E=1600000 edges, 3 GCN steps, dropout p=0.3.
// CSR build: count/scan + 2-phase bucket permutation (write-combine friendly).
// SpMM: wave per node, lane per feature, 8x unrolled gather; dropped features
// stored in bf16 (halves gather traffic, doubles L2 hit rate); f32 accumulate.

typedef __hip_bfloat16 bf16;

constexpr int   N_NODES  = 100000;
constexpr int   D        = 64;
constexpr int   E_EDGES  = 1600000;
constexpr int   ND       = N_NODES * D;
constexpr float P_DROP   = 0.3f;
constexpr float INV_KEEP = 1.0f / (1.0f - P_DROP);

constexpr int SEG         = 512;                          // deg-scan segment
constexpr int SCAN_BLOCKS = (N_NODES + SEG - 1) / SEG;    // 196

constexpr int BROWS   = 512;                              // rows per bucket
constexpr int NB      = (N_NODES + BROWS - 1) / BROWS;    // 196 buckets
constexpr int TILE    = 2048;                             // edges per P2 block
constexpr int EPT     = TILE / 256;                       // 8 edges per thread
constexpr int P2_GRID = (E_EDGES + TILE - 1) / TILE;      // 782

// ---------- degree + rowptr ----------

__global__ void count_deg(const int* __restrict__ rows, int* __restrict__ deg) {
    int e = blockIdx.x * blockDim.x + threadIdx.x;
    if (e < E_EDGES) atomicAdd(&deg[rows[e]], 1);
}

__global__ void scan_block_sums(const int* __restrict__ deg, int* __restrict__ bsum) {
    __shared__ int red[256];
    int base = blockIdx.x * SEG;
    int tid = threadIdx.x;
    int i0 = base + 2 * tid, i1 = i0 + 1;
    int v = 0;
    if (i0 < N_NODES) v += deg[i0];
    if (i1 < N_NODES) v += deg[i1];
    red[tid] = v;
    __syncthreads();
    for (int off = 128; off > 0; off >>= 1) {
        if (tid < off) red[tid] += red[tid + off];
        __syncthreads();
    }
    if (tid == 0) bsum[blockIdx.x] = red[0];
}

__global__ void scan_bsums(const int* __restrict__ bsum, int* __restrict__ boff,
                           int* __restrict__ rowptr) {
    __shared__ int s[256];
    int tid = threadIdx.x;
    int v = (tid < SCAN_BLOCKS) ? bsum[tid] : 0;
    s[tid] = v;
    __syncthreads();
    for (int off = 1; off < 256; off <<= 1) {
        int t = (tid >= off) ? s[tid - off] : 0;
        __syncthreads();
        s[tid] += t;
        __syncthreads();
    }
    if (tid < SCAN_BLOCKS) boff[tid] = s[tid] - v;   // exclusive
    if (tid == 0) rowptr[N_NODES] = E_EDGES;
}

__global__ void scan_write(const int* __restrict__ deg, const int* __restrict__ boff,
                           int* __restrict__ rowptr) {
    __shared__ int s[256];
    int base = blockIdx.x * SEG;
    int tid = threadIdx.x;
    int i0 = base + 2 * tid, i1 = i0 + 1;
    int v0 = (i0 < N_NODES) ? deg[i0] : 0;
    int v1 = (i1 < N_NODES) ? deg[i1] : 0;
    int pair = v0 + v1;
    s[tid] = pair;
    __syncthreads();
    for (int off = 1; off < 256; off <<= 1) {
        int t = (tid >= off) ? s[tid - off] : 0;
        __syncthreads();
        s[tid] += t;
        __syncthreads();
    }
    int excl = boff[blockIdx.x] + s[tid] - pair;
    if (i0 < N_NODES) rowptr[i0] = excl;
    if (i1 < N_NODES) rowptr[i1] = excl + v0;
}

__global__ void init_bcur(const int* __restrict__ rowptr, int* __restrict__ bucket_cursor) {
    int b = threadIdx.x;
    if (b < NB) {
        int r = b * BROWS;
        bucket_cursor[b] = rowptr[r < N_NODES ? r : N_NODES];
    }
}

// ---------- P2: bucket-major scatter ----------
__global__ void bucket_scatter(const int* __restrict__ rows, const int* __restrict__ cols,
                               const float* __restrict__ vals, int* __restrict__ bucket_cursor,
                               int2* __restrict__ tmp) {
    __shared__ int lc[NB];
    __shared__ int gcur[NB];
    int tid = threadIdx.x;
    int base = blockIdx.x * TILE;

    if (tid < NB) lc[tid] = 0;
    __syncthreads();

    int r[EPT], c[EPT], b[EPT];
    float v[EPT];
#pragma unroll
    for (int k = 0; k < EPT; ++k) {
        int e = base + k * 256 + tid;
        if (e < E_EDGES) {
            r[k] = rows[e];
            c[k] = cols[e];
            v[k] = vals[e];
            b[k] = r[k] >> 9;                 // BROWS = 512
            atomicAdd(&lc[b[k]], 1);
        } else {
            b[k] = -1;
        }
    }
    __syncthreads();

    if (tid < NB && lc[tid] > 0)
        gcur[tid] = atomicAdd(&bucket_cursor[tid], lc[tid]);
    __syncthreads();

#pragma unroll
    for (int k = 0; k < EPT; ++k) {
        if (b[k] >= 0) {
            int dest = atomicAdd(&gcur[b[k]], 1);
            int meta = ((r[k] & (BROWS - 1)) << 17) | c[k];
            tmp[dest] = make_int2(meta, __float_as_int(v[k]));
        }
    }
}

// ---------- P3: per-bucket CSR finalize ----------
__global__ void csr_finalize(const int* __restrict__ rowptr, const int2* __restrict__ tmp,
                             int2* __restrict__ sedge) {
    __shared__ int rcur[BROWS];
    int b = blockIdx.x;
    int tid = threadIdx.x;
    int rbase = b * BROWS;
    int rcount = min(BROWS, N_NODES - rbase);

    for (int i = tid; i < rcount; i += 256) rcur[i] = rowptr[rbase + i];
    __syncthreads();

    int seg_beg = rowptr[rbase];
    int seg_end = rowptr[(rbase + BROWS < N_NODES) ? rbase + BROWS : N_NODES];
    for (int i = seg_beg + tid; i < seg_end; i += 256) {
        int2 ev = tmp[i];
        int lr = ev.x >> 17;
        int cc = ev.x & 0x1FFFF;
        int p = atomicAdd(&rcur[lr], 1);
        sedge[p] = make_int2(cc, ev.y);
    }
}

// ---------- layer kernels ----------

// out = h;  t0 = dropout_bf16(h, u0)
__global__ void init_out_dropout(const float4* __restrict__ h, const float4* __restrict__ u,
                                 float4* __restrict__ out, bf16* __restrict__ t, int n4) {
    int i = blockIdx.x * blockDim.x + threadIdx.x;
    if (i >= n4) return;
    float4 c = h[i];
    float4 uu = u[i];
    out[i] = c;
    alignas(8) bf16 tb[4];
    tb[0] = __float2bfloat16((uu.x > P_DROP) ? c.x * INV_KEEP : 0.0f);
    tb[1] = __float2bfloat16((uu.y > P_DROP) ? c.y * INV_KEEP : 0.0f);
    tb[2] = __float2bfloat16((uu.z > P_DROP) ? c.z * INV_KEEP : 0.0f);
    tb[3] = __float2bfloat16((uu.w > P_DROP) ? c.w * INV_KEEP : 0.0f);
    *reinterpret_cast<uint2*>(&t[(size_t)i * 4]) = *reinterpret_cast<uint2*>(tb);
}

// Wave per node, lane per feature; 8-wide unrolled bf16 gather, f32 accumulate.
template <bool HAS_NEXT>
__global__ void spmm_csr(const bf16* __restrict__ t, const int* __restrict__ rowptr,
                         const int2* __restrict__ sedge,
                         const float* __restrict__ u_next, bf16* __restrict__ t_next,
                         float* __restrict__ out, float out_scale) {
    int node = blockIdx.x * (blockDim.x >> 6) + (threadIdx.x >> 6);
    int d = threadIdx.x & 63;
    if (node >= N_NODES) return;
    int beg = rowptr[node];
    int end = rowptr[node + 1];
    float s = 0.0f;
    int i = beg;
    for (; i + 8 <= end; i += 8) {
        int2 e[8];
        float f[8];
#pragma unroll
        for (int k = 0; k < 8; ++k) e[k] = sedge[i + k];
#pragma unroll
        for (int k = 0; k < 8; ++k) f[k] = __bfloat162float(t[(size_t)e[k].x * D + d]);
#pragma unroll
        for (int k = 0; k < 8; ++k) s = fmaf(__int_as_float(e[k].y), f[k], s);
    }
    for (; i < end; ++i) {
        int2 ev = sedge[i];
        s = fmaf(__int_as_float(ev.y), __bfloat162float(t[(size_t)ev.x * D + d]), s);
    }
    size_t idx = (size_t)node * D + d;
    out[idx] = (out[idx] + s) * out_scale;
    if (HAS_NEXT) {
        float uu = u_next[idx];
        t_next[idx] = __float2bfloat16((uu > P_DROP) ? s * INV_KEEP : 0.0f);
    }
}

extern "C" void kernel_launch(void* const* d_in, const int* in_sizes, int n_in,
                              void* d_out, int out_size, void* d_ws, size_t ws_size,
                              hipStream_t stream) {
    const float* h    = (const float*)d_in[0];
    const float* vals = (const float*)d_in[1];
    const float* u    = (const float*)d_in[2];
    const int*   rows = (const int*)d_in[3];
    const int*   cols = (const int*)d_in[4];
    float* out = (float*)d_out;

    // workspace layout (tmp aliases T1: both 12.8 MB; tmp dead before layer 0)
    bf16*  T0     = (bf16*)d_ws;                  // [ND] bf16
    bf16*  T1     = T0 + ND;                      // [ND] bf16
    int2*  tmp    = (int2*)T1;                    // [E]  (alias, build-phase only)
    int2*  sedge  = (int2*)(T1 + ND);             // [E] packed (col, f32 val)
    int*   rowptr = (int*)(sedge + E_EDGES);      // [N+1]
    int*   deg    = rowptr + (N_NODES + 1);       // [N]
    int*   bsum   = deg + N_NODES;                // [SCAN_BLOCKS]
    int*   boff   = bsum + SCAN_BLOCKS;           // [SCAN_BLOCKS]
    int*   bcur   = boff + SCAN_BLOCKS;           // [NB]

    const int n4 = ND / 4;
    dim3 blk(256);
    int gElem = (n4 + 255) / 256;
    int gEdge = (E_EDGES + 255) / 256;
    int gNode = (N_NODES + 3) / 4;

    // ---- CSR build ----
    hipMemsetAsync(deg, 0, (size_t)N_NODES * sizeof(int), stream);
    count_deg<<<gEdge, blk, 0, stream>>>(rows, deg);
    scan_block_sums<<<SCAN_BLOCKS, blk, 0, stream>>>(deg, bsum);
    scan_bsums<<<1, blk, 0, stream>>>(bsum, boff, rowptr);
    scan_write<<<SCAN_BLOCKS, blk, 0, stream>>>(deg, boff, rowptr);
    init_bcur<<<1, blk, 0, stream>>>(rowptr, bcur);
    bucket_scatter<<<P2_GRID, blk, 0, stream>>>(rows, cols, vals, bcur, tmp);
    csr_finalize<<<NB, blk, 0, stream>>>(rowptr, tmp, sedge);

    // ---- layer 0 prologue: out = h, T0 = dropout(h, u0) ----
    init_out_dropout<<<gElem, blk, 0, stream>>>((const float4*)h, (const float4*)u,
                                                (float4*)out, T0, n4);

    // ---- layers ----
    spmm_csr<true><<<gNode, blk, 0, stream>>>(T0, rowptr, sedge,
                                              u + (size_t)1 * ND, T1, out, 1.0f);
    spmm_csr<true><<<gNode, blk, 0, stream>>>(T1, rowptr, sedge,
                                              u + (size_t)2 * ND, T0, out, 1.0f);
    spmm_csr<false><<<gNode, blk, 0, stream>>>(T0, rowptr, sedge,
                                               nullptr, nullptr, out, 0.25f);
}

// Round 7
// 298.843 us; speedup vs baseline: 3.8164x; 1.2243x over previous
//
#include <hip/hip_runtime.h>
#include <hip/hip_bf16.h>

// GCN: N=100000 nodes, D=64, E=1600000 edges, 3 GCN steps, dropout p=0.3.
// CSR build: count/scan + 2-phase bucket permutation (write-combine friendly).
// SpMM: HALF-wave per node (32 lanes x packed-bf16-pair), so each 64-lane wave
// runs 2 independent edge chains -> 2x memory-level parallelism vs wave/node.
// 8x unrolled gather, f32 accumulate, fused dropout/accum epilogue.

typedef __hip_bfloat16 bf16;

constexpr int   N_NODES  = 100000;
constexpr int   D        = 64;
constexpr int   E_EDGES  = 1600000;
constexpr int   ND       = N_NODES * D;
constexpr float P_DROP   = 0.3f;
constexpr float INV_KEEP = 1.0f / (1.0f - P_DROP);

constexpr int SEG         = 512;                          // deg-scan segment
constexpr int SCAN_BLOCKS = (N_NODES + SEG - 1) / SEG;    // 196

constexpr int BROWS   = 512;                              // rows per bucket
constexpr int NB      = (N_NODES + BROWS - 1) / BROWS;    // 196 buckets
constexpr int TILE    = 2048;                             // edges per P2 block
constexpr int EPT     = TILE / 256;                       // 8 edges per thread
constexpr int P2_GRID = (E_EDGES + TILE - 1) / TILE;      // 782

// ---------- degree + rowptr ----------

__global__ void count_deg(const int* __restrict__ rows, int* __restrict__ deg) {
    int e = blockIdx.x * blockDim.x + threadIdx.x;
    if (e < E_EDGES) atomicAdd(&deg[rows[e]], 1);
}

__global__ void scan_block_sums(const int* __restrict__ deg, int* __restrict__ bsum) {
    __shared__ int red[256];
    int base = blockIdx.x * SEG;
    int tid = threadIdx.x;
    int i0 = base + 2 * tid, i1 = i0 + 1;
    int v = 0;
    if (i0 < N_NODES) v += deg[i0];
    if (i1 < N_NODES) v += deg[i1];
    red[tid] = v;
    __syncthreads();
    for (int off = 128; off > 0; off >>= 1) {
        if (tid < off) red[tid] += red[tid + off];
        __syncthreads();
    }
    if (tid == 0) bsum[blockIdx.x] = red[0];
}

__global__ void scan_bsums(const int* __restrict__ bsum, int* __restrict__ boff,
                           int* __restrict__ rowptr) {
    __shared__ int s[256];
    int tid = threadIdx.x;
    int v = (tid < SCAN_BLOCKS) ? bsum[tid] : 0;
    s[tid] = v;
    __syncthreads();
    for (int off = 1; off < 256; off <<= 1) {
        int t = (tid >= off) ? s[tid - off] : 0;
        __syncthreads();
        s[tid] += t;
        __syncthreads();
    }
    if (tid < SCAN_BLOCKS) boff[tid] = s[tid] - v;   // exclusive
    if (tid == 0) rowptr[N_NODES] = E_EDGES;
}

__global__ void scan_write(const int* __restrict__ deg, const int* __restrict__ boff,
                           int* __restrict__ rowptr) {
    __shared__ int s[256];
    int base = blockIdx.x * SEG;
    int tid = threadIdx.x;
    int i0 = base + 2 * tid, i1 = i0 + 1;
    int v0 = (i0 < N_NODES) ? deg[i0] : 0;
    int v1 = (i1 < N_NODES) ? deg[i1] : 0;
    int pair = v0 + v1;
    s[tid] = pair;
    __syncthreads();
    for (int off = 1; off < 256; off <<= 1) {
        int t = (tid >= off) ? s[tid - off] : 0;
        __syncthreads();
        s[tid] += t;
        __syncthreads();
    }
    int excl = boff[blockIdx.x] + s[tid] - pair;
    if (i0 < N_NODES) rowptr[i0] = excl;
    if (i1 < N_NODES) rowptr[i1] = excl + v0;
}

__global__ void init_bcur(const int* __restrict__ rowptr, int* __restrict__ bucket_cursor) {
    int b = threadIdx.x;
    if (b < NB) {
        int r = b * BROWS;
        bucket_cursor[b] = rowptr[r < N_NODES ? r : N_NODES];
    }
}

// ---------- P2: bucket-major scatter ----------
__global__ void bucket_scatter(const int* __restrict__ rows, const int* __restrict__ cols,
                               const float* __restrict__ vals, int* __restrict__ bucket_cursor,
                               int2* __restrict__ tmp) {
    __shared__ int lc[NB];
    __shared__ int gcur[NB];
    int tid = threadIdx.x;
    int base = blockIdx.x * TILE;

    if (tid < NB) lc[tid] = 0;
    __syncthreads();

    int r[EPT], c[EPT], b[EPT];
    float v[EPT];
#pragma unroll
    for (int k = 0; k < EPT; ++k) {
        int e = base + k * 256 + tid;
        if (e < E_EDGES) {
            r[k] = rows[e];
            c[k] = cols[e];
            v[k] = vals[e];
            b[k] = r[k] >> 9;                 // BROWS = 512
            atomicAdd(&lc[b[k]], 1);
        } else {
            b[k] = -1;
        }
    }
    __syncthreads();

    if (tid < NB && lc[tid] > 0)
        gcur[tid] = atomicAdd(&bucket_cursor[tid], lc[tid]);
    __syncthreads();

#pragma unroll
    for (int k = 0; k < EPT; ++k) {
        if (b[k] >= 0) {
            int dest = atomicAdd(&gcur[b[k]], 1);
            int meta = ((r[k] & (BROWS - 1)) << 17) | c[k];
            tmp[dest] = make_int2(meta, __float_as_int(v[k]));
        }
    }
}

// ---------- P3: per-bucket CSR finalize ----------
__global__ void csr_finalize(const int* __restrict__ rowptr, const int2* __restrict__ tmp,
                             int2* __restrict__ sedge) {
    __shared__ int rcur[BROWS];
    int b = blockIdx.x;
    int tid = threadIdx.x;
    int rbase = b * BROWS;
    int rcount = min(BROWS, N_NODES - rbase);

    for (int i = tid; i < rcount; i += 256) rcur[i] = rowptr[rbase + i];
    __syncthreads();

    int seg_beg = rowptr[rbase];
    int seg_end = rowptr[(rbase + BROWS < N_NODES) ? rbase + BROWS : N_NODES];
    for (int i = seg_beg + tid; i < seg_end; i += 256) {
        int2 ev = tmp[i];
        int lr = ev.x >> 17;
        int cc = ev.x & 0x1FFFF;
        int p = atomicAdd(&rcur[lr], 1);
        sedge[p] = make_int2(cc, ev.y);
    }
}

// ---------- layer kernels ----------

// out = h;  t0 = dropout_bf16(h, u0)
__global__ void init_out_dropout(const float4* __restrict__ h, const float4* __restrict__ u,
                                 float4* __restrict__ out, bf16* __restrict__ t, int n4) {
    int i = blockIdx.x * blockDim.x + threadIdx.x;
    if (i >= n4) return;
    float4 c = h[i];
    float4 uu = u[i];
    out[i] = c;
    alignas(8) bf16 tb[4];
    tb[0] = __float2bfloat16((uu.x > P_DROP) ? c.x * INV_KEEP : 0.0f);
    tb[1] = __float2bfloat16((uu.y > P_DROP) ? c.y * INV_KEEP : 0.0f);
    tb[2] = __float2bfloat16((uu.z > P_DROP) ? c.z * INV_KEEP : 0.0f);
    tb[3] = __float2bfloat16((uu.w > P_DROP) ? c.w * INV_KEEP : 0.0f);
    *reinterpret_cast<uint2*>(&t[(size_t)i * 4]) = *reinterpret_cast<uint2*>(tb);
}

__device__ __forceinline__ unsigned short bf16_bits(float x) {
    bf16 b = __float2bfloat16(x);
    union { bf16 h; unsigned short u; } cv;
    cv.h = b;
    return cv.u;
}

// Half-wave (32 lanes) per node; lane handles feature pair (2*lane, 2*lane+1)
// via one packed-uint gather. Two independent edge chains per 64-lane wave.
template <bool HAS_NEXT>
__global__ void spmm_csr(const unsigned int* __restrict__ t32, const int* __restrict__ rowptr,
                         const int2* __restrict__ sedge,
                         const float2* __restrict__ u2_next, unsigned int* __restrict__ t32_next,
                         float2* __restrict__ out2, float out_scale) {
    int half_id = blockIdx.x * (blockDim.x >> 5) + (threadIdx.x >> 5);  // global half-wave id
    int lane = threadIdx.x & 31;
    int node = half_id;
    if (node >= N_NODES) return;
    int beg = rowptr[node];
    int end = rowptr[node + 1];
    float s0 = 0.0f, s1 = 0.0f;
    int i = beg;
    for (; i + 8 <= end; i += 8) {
        int2 e[8];
        unsigned int p[8];
#pragma unroll
        for (int k = 0; k < 8; ++k) e[k] = sedge[i + k];
#pragma unroll
        for (int k = 0; k < 8; ++k) p[k] = t32[(size_t)e[k].x * 32 + lane];
#pragma unroll
        for (int k = 0; k < 8; ++k) {
            float v  = __int_as_float(e[k].y);
            float f0 = __int_as_float(p[k] << 16);          // feature 2*lane
            float f1 = __int_as_float(p[k] & 0xFFFF0000u);  // feature 2*lane+1
            s0 = fmaf(v, f0, s0);
            s1 = fmaf(v, f1, s1);
        }
    }
    for (; i < end; ++i) {
        int2 ev = sedge[i];
        unsigned int p = t32[(size_t)ev.x * 32 + lane];
        float v = __int_as_float(ev.y);
        s0 = fmaf(v, __int_as_float(p << 16), s0);
        s1 = fmaf(v, __int_as_float(p & 0xFFFF0000u), s1);
    }
    size_t idx2 = (size_t)node * 32 + lane;    // float2 / uint granularity
    float2 o = out2[idx2];
    o.x = (o.x + s0) * out_scale;
    o.y = (o.y + s1) * out_scale;
    out2[idx2] = o;
    if (HAS_NEXT) {
        float2 uu = u2_next[idx2];
        float d0 = (uu.x > P_DROP) ? s0 * INV_KEEP : 0.0f;
        float d1 = (uu.y > P_DROP) ? s1 * INV_KEEP : 0.0f;
        t32_next[idx2] = (unsigned int)bf16_bits(d0) | ((unsigned int)bf16_bits(d1) << 16);
    }
}

extern "C" void kernel_launch(void* const* d_in, const int* in_sizes, int n_in,
                              void* d_out, int out_size, void* d_ws, size_t ws_size,
                              hipStream_t stream) {
    const float* h    = (const float*)d_in[0];
    const float* vals = (const float*)d_in[1];
    const float* u    = (const float*)d_in[2];
    const int*   rows = (const int*)d_in[3];
    const int*   cols = (const int*)d_in[4];
    float* out = (float*)d_out;

    // workspace layout (tmp aliases T1: both 12.8 MB; tmp dead before layer 0)
    bf16*  T0     = (bf16*)d_ws;                  // [ND] bf16
    bf16*  T1     = T0 + ND;                      // [ND] bf16
    int2*  tmp    = (int2*)T1;                    // [E]  (alias, build-phase only)
    int2*  sedge  = (int2*)(T1 + ND);             // [E] packed (col, f32 val)
    int*   rowptr = (int*)(sedge + E_EDGES);      // [N+1]
    int*   deg    = rowptr + (N_NODES + 1);       // [N]
    int*   bsum   = deg + N_NODES;                // [SCAN_BLOCKS]
    int*   boff   = bsum + SCAN_BLOCKS;           // [SCAN_BLOCKS]
    int*   bcur   = boff + SCAN_BLOCKS;           // [NB]

    const int n4 = ND / 4;
    dim3 blk(256);
    int gElem = (n4 + 255) / 256;
    int gEdge = (E_EDGES + 255) / 256;
    int gNode = (N_NODES + 7) / 8;   // 8 half-waves (nodes) per 256-thread block

    // ---- CSR build ----
    hipMemsetAsync(deg, 0, (size_t)N_NODES * sizeof(int), stream);
    count_deg<<<gEdge, blk, 0, stream>>>(rows, deg);
    scan_block_sums<<<SCAN_BLOCKS, blk, 0, stream>>>(deg, bsum);
    scan_bsums<<<1, blk, 0, stream>>>(bsum, boff, rowptr);
    scan_write<<<SCAN_BLOCKS, blk, 0, stream>>>(deg, boff, rowptr);
    init_bcur<<<1, blk, 0, stream>>>(rowptr, bcur);
    bucket_scatter<<<P2_GRID, blk, 0, stream>>>(rows, cols, vals, bcur, tmp);
    csr_finalize<<<NB, blk, 0, stream>>>(rowptr, tmp, sedge);

    // ---- layer 0 prologue: out = h, T0 = dropout(h, u0) ----
    init_out_dropout<<<gElem, blk, 0, stream>>>((const float4*)h, (const float4*)u,
                                                (float4*)out, T0, n4);

    // ---- layers ----
    spmm_csr<true><<<gNode, blk, 0, stream>>>((const unsigned int*)T0, rowptr, sedge,
                                              (const float2*)(u + (size_t)1 * ND),
                                              (unsigned int*)T1, (float2*)out, 1.0f);
    spmm_csr<true><<<gNode, blk, 0, stream>>>((const unsigned int*)T1, rowptr, sedge,
                                              (const float2*)(u + (size_t)2 * ND),
                                              (unsigned int*)T0, (float2*)out, 1.0f);
    spmm_csr<false><<<gNode, blk, 0, stream>>>((const unsigned int*)T0, rowptr, sedge,
                                               nullptr, nullptr, (float2*)out, 0.25f);
}

// Round 8
// 277.379 us; speedup vs baseline: 4.1117x; 1.0774x over previous
//
#include <hip/hip_runtime.h>
#include <hip/hip_bf16.h>

// GCN: N=100000 nodes, D=64, E=1600000 edges, 3 GCN steps, dropout p=0.3.
// CSR build: count/scan + 2-phase bucket permutation (write-combine friendly).
// SpMM: QUARTER-wave per node (16 lanes x uint2 = 4 packed bf16), so each
// 64-lane wave runs 4 independent edge chains and each gather instruction
// retires 4 edges. Batches of 8 edges with clamped-index padding (no serial
// remainder). f32 accumulate, fused dropout/accum epilogue.

typedef __hip_bfloat16 bf16;

constexpr int   N_NODES  = 100000;
constexpr int   D        = 64;
constexpr int   E_EDGES  = 1600000;
constexpr int   ND       = N_NODES * D;
constexpr float P_DROP   = 0.3f;
constexpr float INV_KEEP = 1.0f / (1.0f - P_DROP);

constexpr int SEG         = 512;                          // deg-scan segment
constexpr int SCAN_BLOCKS = (N_NODES + SEG - 1) / SEG;    // 196

constexpr int BROWS   = 512;                              // rows per bucket
constexpr int NB      = (N_NODES + BROWS - 1) / BROWS;    // 196 buckets
constexpr int TILE    = 2048;                             // edges per P2 block
constexpr int EPT     = TILE / 256;                       // 8 edges per thread
constexpr int P2_GRID = (E_EDGES + TILE - 1) / TILE;      // 782

// ---------- degree + rowptr ----------

__global__ void count_deg(const int* __restrict__ rows, int* __restrict__ deg) {
    int e = blockIdx.x * blockDim.x + threadIdx.x;
    if (e < E_EDGES) atomicAdd(&deg[rows[e]], 1);
}

__global__ void scan_block_sums(const int* __restrict__ deg, int* __restrict__ bsum) {
    __shared__ int red[256];
    int base = blockIdx.x * SEG;
    int tid = threadIdx.x;
    int i0 = base + 2 * tid, i1 = i0 + 1;
    int v = 0;
    if (i0 < N_NODES) v += deg[i0];
    if (i1 < N_NODES) v += deg[i1];
    red[tid] = v;
    __syncthreads();
    for (int off = 128; off > 0; off >>= 1) {
        if (tid < off) red[tid] += red[tid + off];
        __syncthreads();
    }
    if (tid == 0) bsum[blockIdx.x] = red[0];
}

__global__ void scan_bsums(const int* __restrict__ bsum, int* __restrict__ boff,
                           int* __restrict__ rowptr) {
    __shared__ int s[256];
    int tid = threadIdx.x;
    int v = (tid < SCAN_BLOCKS) ? bsum[tid] : 0;
    s[tid] = v;
    __syncthreads();
    for (int off = 1; off < 256; off <<= 1) {
        int t = (tid >= off) ? s[tid - off] : 0;
        __syncthreads();
        s[tid] += t;
        __syncthreads();
    }
    if (tid < SCAN_BLOCKS) boff[tid] = s[tid] - v;   // exclusive
    if (tid == 0) rowptr[N_NODES] = E_EDGES;
}

__global__ void scan_write(const int* __restrict__ deg, const int* __restrict__ boff,
                           int* __restrict__ rowptr) {
    __shared__ int s[256];
    int base = blockIdx.x * SEG;
    int tid = threadIdx.x;
    int i0 = base + 2 * tid, i1 = i0 + 1;
    int v0 = (i0 < N_NODES) ? deg[i0] : 0;
    int v1 = (i1 < N_NODES) ? deg[i1] : 0;
    int pair = v0 + v1;
    s[tid] = pair;
    __syncthreads();
    for (int off = 1; off < 256; off <<= 1) {
        int t = (tid >= off) ? s[tid - off] : 0;
        __syncthreads();
        s[tid] += t;
        __syncthreads();
    }
    int excl = boff[blockIdx.x] + s[tid] - pair;
    if (i0 < N_NODES) rowptr[i0] = excl;
    if (i1 < N_NODES) rowptr[i1] = excl + v0;
}

__global__ void init_bcur(const int* __restrict__ rowptr, int* __restrict__ bucket_cursor) {
    int b = threadIdx.x;
    if (b < NB) {
        int r = b * BROWS;
        bucket_cursor[b] = rowptr[r < N_NODES ? r : N_NODES];
    }
}

// ---------- P2: bucket-major scatter ----------
__global__ void bucket_scatter(const int* __restrict__ rows, const int* __restrict__ cols,
                               const float* __restrict__ vals, int* __restrict__ bucket_cursor,
                               int2* __restrict__ tmp) {
    __shared__ int lc[NB];
    __shared__ int gcur[NB];
    int tid = threadIdx.x;
    int base = blockIdx.x * TILE;

    if (tid < NB) lc[tid] = 0;
    __syncthreads();

    int r[EPT], c[EPT], b[EPT];
    float v[EPT];
#pragma unroll
    for (int k = 0; k < EPT; ++k) {
        int e = base + k * 256 + tid;
        if (e < E_EDGES) {
            r[k] = rows[e];
            c[k] = cols[e];
            v[k] = vals[e];
            b[k] = r[k] >> 9;                 // BROWS = 512
            atomicAdd(&lc[b[k]], 1);
        } else {
            b[k] = -1;
        }
    }
    __syncthreads();

    if (tid < NB && lc[tid] > 0)
        gcur[tid] = atomicAdd(&bucket_cursor[tid], lc[tid]);
    __syncthreads();

#pragma unroll
    for (int k = 0; k < EPT; ++k) {
        if (b[k] >= 0) {
            int dest = atomicAdd(&gcur[b[k]], 1);
            int meta = ((r[k] & (BROWS - 1)) << 17) | c[k];
            tmp[dest] = make_int2(meta, __float_as_int(v[k]));
        }
    }
}

// ---------- P3: per-bucket CSR finalize ----------
__global__ void csr_finalize(const int* __restrict__ rowptr, const int2* __restrict__ tmp,
                             int2* __restrict__ sedge) {
    __shared__ int rcur[BROWS];
    int b = blockIdx.x;
    int tid = threadIdx.x;
    int rbase = b * BROWS;
    int rcount = min(BROWS, N_NODES - rbase);

    for (int i = tid; i < rcount; i += 256) rcur[i] = rowptr[rbase + i];
    __syncthreads();

    int seg_beg = rowptr[rbase];
    int seg_end = rowptr[(rbase + BROWS < N_NODES) ? rbase + BROWS : N_NODES];
    for (int i = seg_beg + tid; i < seg_end; i += 256) {
        int2 ev = tmp[i];
        int lr = ev.x >> 17;
        int cc = ev.x & 0x1FFFF;
        int p = atomicAdd(&rcur[lr], 1);
        sedge[p] = make_int2(cc, ev.y);
    }
}

// ---------- layer kernels ----------

// out = h;  t0 = dropout_bf16(h, u0)
__global__ void init_out_dropout(const float4* __restrict__ h, const float4* __restrict__ u,
                                 float4* __restrict__ out, bf16* __restrict__ t, int n4) {
    int i = blockIdx.x * blockDim.x + threadIdx.x;
    if (i >= n4) return;
    float4 c = h[i];
    float4 uu = u[i];
    out[i] = c;
    alignas(8) bf16 tb[4];
    tb[0] = __float2bfloat16((uu.x > P_DROP) ? c.x * INV_KEEP : 0.0f);
    tb[1] = __float2bfloat16((uu.y > P_DROP) ? c.y * INV_KEEP : 0.0f);
    tb[2] = __float2bfloat16((uu.z > P_DROP) ? c.z * INV_KEEP : 0.0f);
    tb[3] = __float2bfloat16((uu.w > P_DROP) ? c.w * INV_KEEP : 0.0f);
    *reinterpret_cast<uint2*>(&t[(size_t)i * 4]) = *reinterpret_cast<uint2*>(tb);
}

__device__ __forceinline__ unsigned short bf16_bits(float x) {
    bf16 b = __float2bfloat16(x);
    union { bf16 h; unsigned short u; } cv;
    cv.h = b;
    return cv.u;
}

// Quarter-wave (16 lanes) per node; lane handles features 4*lane..4*lane+3
// via one uint2 gather (4 packed bf16). Four independent edge chains per wave.
// Edge batches of 8 with clamped-index padding: no serial remainder loop.
template <bool HAS_NEXT>
__global__ void spmm_csr(const uint2* __restrict__ t2, const int* __restrict__ rowptr,
                         const int2* __restrict__ sedge,
                         const float4* __restrict__ u4_next, uint2* __restrict__ t2_next,
                         float4* __restrict__ out4, float out_scale) {
    int node = blockIdx.x * (blockDim.x >> 4) + (threadIdx.x >> 4);
    int lane = threadIdx.x & 15;
    if (node >= N_NODES) return;
    int beg = rowptr[node];
    int end = rowptr[node + 1];
    float s0 = 0.0f, s1 = 0.0f, s2 = 0.0f, s3 = 0.0f;
    for (int i = beg; i < end; i += 8) {
        int2 e[8];
        uint2 p[8];
#pragma unroll
        for (int k = 0; k < 8; ++k) {
            int idx = (i + k < end) ? (i + k) : beg;   // beg<end inside this loop
            e[k] = sedge[idx];
        }
#pragma unroll
        for (int k = 0; k < 8; ++k) p[k] = t2[(size_t)e[k].x * 16 + lane];
#pragma unroll
        for (int k = 0; k < 8; ++k) {
            float v = (i + k < end) ? __int_as_float(e[k].y) : 0.0f;
            s0 = fmaf(v, __int_as_float(p[k].x << 16), s0);
            s1 = fmaf(v, __int_as_float(p[k].x & 0xFFFF0000u), s1);
            s2 = fmaf(v, __int_as_float(p[k].y << 16), s2);
            s3 = fmaf(v, __int_as_float(p[k].y & 0xFFFF0000u), s3);
        }
    }
    size_t idx4 = (size_t)node * 16 + lane;    // float4 / uint2 granularity
    float4 o = out4[idx4];
    o.x = (o.x + s0) * out_scale;
    o.y = (o.y + s1) * out_scale;
    o.z = (o.z + s2) * out_scale;
    o.w = (o.w + s3) * out_scale;
    out4[idx4] = o;
    if (HAS_NEXT) {
        float4 uu = u4_next[idx4];
        float d0 = (uu.x > P_DROP) ? s0 * INV_KEEP : 0.0f;
        float d1 = (uu.y > P_DROP) ? s1 * INV_KEEP : 0.0f;
        float d2 = (uu.z > P_DROP) ? s2 * INV_KEEP : 0.0f;
        float d3 = (uu.w > P_DROP) ? s3 * INV_KEEP : 0.0f;
        uint2 pk;
        pk.x = (unsigned int)bf16_bits(d0) | ((unsigned int)bf16_bits(d1) << 16);
        pk.y = (unsigned int)bf16_bits(d2) | ((unsigned int)bf16_bits(d3) << 16);
        t2_next[idx4] = pk;
    }
}

extern "C" void kernel_launch(void* const* d_in, const int* in_sizes, int n_in,
                              void* d_out, int out_size, void* d_ws, size_t ws_size,
                              hipStream_t stream) {
    const float* h    = (const float*)d_in[0];
    const float* vals = (const float*)d_in[1];
    const float* u    = (const float*)d_in[2];
    const int*   rows = (const int*)d_in[3];
    const int*   cols = (const int*)d_in[4];
    float* out = (float*)d_out;

    // workspace layout (tmp aliases T1: both 12.8 MB; tmp dead before layer 0)
    bf16*  T0     = (bf16*)d_ws;                  // [ND] bf16
    bf16*  T1     = T0 + ND;                      // [ND] bf16
    int2*  tmp    = (int2*)T1;                    // [E]  (alias, build-phase only)
    int2*  sedge  = (int2*)(T1 + ND);             // [E] packed (col, f32 val)
    int*   rowptr = (int*)(sedge + E_EDGES);      // [N+1]
    int*   deg    = rowptr + (N_NODES + 1);       // [N]
    int*   bsum   = deg + N_NODES;                // [SCAN_BLOCKS]
    int*   boff   = bsum + SCAN_BLOCKS;           // [SCAN_BLOCKS]
    int*   bcur   = boff + SCAN_BLOCKS;           // [NB]

    const int n4 = ND / 4;
    dim3 blk(256);
    int gElem = (n4 + 255) / 256;
    int gEdge = (E_EDGES + 255) / 256;
    int gNode = (N_NODES + 15) / 16;  // 16 quarter-waves (nodes) per 256-thread block

    // ---- CSR build ----
    hipMemsetAsync(deg, 0, (size_t)N_NODES * sizeof(int), stream);
    count_deg<<<gEdge, blk, 0, stream>>>(rows, deg);
    scan_block_sums<<<SCAN_BLOCKS, blk, 0, stream>>>(deg, bsum);
    scan_bsums<<<1, blk, 0, stream>>>(bsum, boff, rowptr);
    scan_write<<<SCAN_BLOCKS, blk, 0, stream>>>(deg, boff, rowptr);
    init_bcur<<<1, blk, 0, stream>>>(rowptr, bcur);
    bucket_scatter<<<P2_GRID, blk, 0, stream>>>(rows, cols, vals, bcur, tmp);
    csr_finalize<<<NB, blk, 0, stream>>>(rowptr, tmp, sedge);

    // ---- layer 0 prologue: out = h, T0 = dropout(h, u0) ----
    init_out_dropout<<<gElem, blk, 0, stream>>>((const float4*)h, (const float4*)u,
                                                (float4*)out, T0, n4);

    // ---- layers ----
    spmm_csr<true><<<gNode, blk, 0, stream>>>((const uint2*)T0, rowptr, sedge,
                                              (const float4*)(u + (size_t)1 * ND),
                                              (uint2*)T1, (float4*)out, 1.0f);
    spmm_csr<true><<<gNode, blk, 0, stream>>>((const uint2*)T1, rowptr, sedge,
                                              (const float4*)(u + (size_t)2 * ND),
                                              (uint2*)T0, (float4*)out, 1.0f);
    spmm_csr<false><<<gNode, blk, 0, stream>>>((const uint2*)T0, rowptr, sedge,
                                               nullptr, nullptr, (float4*)out, 0.25f);
}